// Round 5
// baseline (91.358 us; speedup 1.0000x reference)
//
#include <hip/hip_runtime.h>
#include <hip/hip_bf16.h>

#define BC 4
#define NQ 1200
#define DIM 256
#define NH 8
#define HD 32
#define E3 768
#define MROWS (BC*NQ)
#define KPAD 1280
#define SCALE 0.17677669529663687f
#define L2E 1.4426950408889634f

typedef __attribute__((ext_vector_type(8))) short bf16x8;
typedef __attribute__((ext_vector_type(4))) float f32x4;

__device__ inline short f2bf(float f) {
    __hip_bfloat16 h = __float2bfloat16(f);
    return *reinterpret_cast<short*>(&h);
}
__device__ inline unsigned pack2bf(float a, float b) {
    unsigned ua = (unsigned short)f2bf(a);
    unsigned ub = (unsigned short)f2bf(b);
    return ua | (ub << 16);
}

// ---------------- beta (f32 exact) + center packing ----------------
__global__ void beta_ctr_kernel(const float* __restrict__ feat, const float* __restrict__ bw,
                                const float* __restrict__ bb, const float* __restrict__ bbox,
                                float* __restrict__ beta, float* __restrict__ ctr) {
    int gw = (blockIdx.x * 256 + threadIdx.x) >> 6;   // one wave per (b,n)
    int lane = threadIdx.x & 63;
    if (gw >= MROWS) return;
    const float* frow = feat + (size_t)gw * DIM;
    float acc[NH];
#pragma unroll
    for (int h = 0; h < NH; ++h) acc[h] = 0.f;
#pragma unroll
    for (int it = 0; it < DIM / 64; ++it) {
        int d = it * 64 + lane;
        float f = frow[d];
#pragma unroll
        for (int h = 0; h < NH; ++h) acc[h] += f * bw[h * DIM + d];
    }
#pragma unroll
    for (int h = 0; h < NH; ++h) {
#pragma unroll
        for (int off = 32; off; off >>= 1) acc[h] += __shfl_xor(acc[h], off);
    }
    int b = gw / NQ, n = gw % NQ;
#pragma unroll
    for (int h = 0; h < NH; ++h) {
        float v = acc[h] + bb[h];
        if (lane == h) beta[(b * NH + h) * NQ + n] = v;
    }
    if (lane == 0) {
        ctr[gw * 2]     = bbox[(size_t)gw * 10];
        ctr[gw * 2 + 1] = bbox[(size_t)gw * 10 + 1];
    }
}

// ---------------- GEMM: C[M,E] = A[M,256] * W[E,256]^T + bias ----------------
// VTOUT: for e in [512,768) (the V projection), write transposed VT[b][h][d][key]
// instead of the row-major C — the 4 per-lane C rows are 4 consecutive keys = short4.
template<bool AF32, bool BF32, bool OUTF32, bool VTOUT>
__global__ __launch_bounds__(256) void gemm_k256(const void* __restrict__ Av,
                                                 const void* __restrict__ Bv,
                                                 const float* __restrict__ bias,
                                                 void* __restrict__ Cout, int Edim,
                                                 short* __restrict__ vtout) {
    __shared__ short as[64][40];
    __shared__ short bs[64][40];
    int m0 = blockIdx.y * 64, e0 = blockIdx.x * 64;
    int t = threadIdx.x, lane = t & 63, wid = t >> 6;
    int wr = (wid >> 1) * 32, wc = (wid & 1) * 32;
    f32x4 acc[2][2] = {};
    int lrow = t >> 2, lch = t & 3;

    for (int ks = 0; ks < DIM / 32; ++ks) {
        bf16x8 av, wv;
        if (AF32) {
            const float* A = (const float*)Av;
            float4 f0 = *(const float4*)(A + (size_t)(m0 + lrow) * DIM + ks * 32 + lch * 8);
            float4 f1 = *(const float4*)(A + (size_t)(m0 + lrow) * DIM + ks * 32 + lch * 8 + 4);
            av[0]=f2bf(f0.x); av[1]=f2bf(f0.y); av[2]=f2bf(f0.z); av[3]=f2bf(f0.w);
            av[4]=f2bf(f1.x); av[5]=f2bf(f1.y); av[6]=f2bf(f1.z); av[7]=f2bf(f1.w);
        } else {
            av = *(const bf16x8*)((const short*)Av + (size_t)(m0 + lrow) * DIM + ks * 32 + lch * 8);
        }
        if (BF32) {
            const float* B = (const float*)Bv;
            float4 f0 = *(const float4*)(B + (size_t)(e0 + lrow) * DIM + ks * 32 + lch * 8);
            float4 f1 = *(const float4*)(B + (size_t)(e0 + lrow) * DIM + ks * 32 + lch * 8 + 4);
            wv[0]=f2bf(f0.x); wv[1]=f2bf(f0.y); wv[2]=f2bf(f0.z); wv[3]=f2bf(f0.w);
            wv[4]=f2bf(f1.x); wv[5]=f2bf(f1.y); wv[6]=f2bf(f1.z); wv[7]=f2bf(f1.w);
        } else {
            wv = *(const bf16x8*)((const short*)Bv + (size_t)(e0 + lrow) * DIM + ks * 32 + lch * 8);
        }
        __syncthreads();
        *(bf16x8*)&as[lrow][lch * 8] = av;
        *(bf16x8*)&bs[lrow][lch * 8] = wv;
        __syncthreads();
#pragma unroll
        for (int sm = 0; sm < 2; ++sm) {
            bf16x8 af = *(const bf16x8*)&as[wr + sm * 16 + (lane & 15)][(lane >> 4) * 8];
#pragma unroll
            for (int sn = 0; sn < 2; ++sn) {
                bf16x8 bfv = *(const bf16x8*)&bs[wc + sn * 16 + (lane & 15)][(lane >> 4) * 8];
                acc[sm][sn] = __builtin_amdgcn_mfma_f32_16x16x32_bf16(af, bfv, acc[sm][sn], 0, 0, 0);
            }
        }
    }
#pragma unroll
    for (int sm = 0; sm < 2; ++sm)
#pragma unroll
        for (int sn = 0; sn < 2; ++sn) {
            int e = e0 + wc + sn * 16 + (lane & 15);
            float bv = bias[e];
            float vals[4];
            int mbase = m0 + wr + sm * 16 + (lane >> 4) * 4;
#pragma unroll
            for (int r = 0; r < 4; ++r) vals[r] = acc[sm][sn][r] + bv;
            if (VTOUT && e >= 2 * DIM) {
                int dv = e - 2 * DIM;
                int hv = dv >> 5, dd = dv & 31;
                int bb = mbase / NQ, nn = mbase - bb * NQ;   // 4-key group never crosses b
                short4 o;
                o.x = f2bf(vals[0]); o.y = f2bf(vals[1]);
                o.z = f2bf(vals[2]); o.w = f2bf(vals[3]);
                *(short4*)&vtout[(((size_t)bb * NH + hv) * HD + dd) * KPAD + nn] = o;
            } else {
#pragma unroll
                for (int r = 0; r < 4; ++r) {
                    int m = mbase + r;
                    if (OUTF32) ((float*)Cout)[(size_t)m * Edim + e] = vals[r];
                    else        ((short*)Cout)[(size_t)m * Edim + e] = f2bf(vals[r]);
                }
            }
        }
}

// ---------------- fused flash attention ----------------
// grid: (38, B*H); block 256 = 4 waves: wave = (qgroup<<1)|ksplit.
// K frags + V^T frags + centers from global (L2). P staged through wave-private
// LDS (R2-proven layout). NO barriers in the main loop; one before final merge.
__global__ __launch_bounds__(256) void attn_kernel(const short* __restrict__ qkv,
                                                   const short* __restrict__ vt,
                                                   const float* __restrict__ beta,
                                                   const float* __restrict__ ctr,
                                                   short* __restrict__ attnb) {
    // union: per-wave P staging pl[4][16][72]sh (9216 B) / merge mrg[4][64][10]f (10240 B)
    __shared__ __align__(16) char smem[10240];

    const int t = threadIdx.x, lane = t & 63, w = t >> 6;
    const int g = lane >> 4, i = lane & 15;
    const int qg = w >> 1, ksp = w & 1;
    const int bh = blockIdx.y, b = bh >> 3, h = bh & 7;
    const int q0 = blockIdx.x * 32 + qg * 16;
    const int q = q0 + i, qc = min(q, NQ - 1);
    const int kwb = ksp * 64;

    bf16x8 qf = *(const bf16x8*)(qkv + (size_t)(b * NQ + qc) * E3 + h * HD + g * 8);
    const float cqx = ctr[(b * NQ + qc) * 2];
    const float cqy = ctr[(b * NQ + qc) * 2 + 1];
    const float bql = beta[(b * NH + h) * NQ + qc] * L2E;
    const float SL2E = SCALE * L2E;

    float mcur = -1e30f, lsum = 0.f;
    f32x4 o0 = {}, o1 = {};

    const short* kgb = qkv + (size_t)b * NQ * E3 + DIM + h * HD + g * 8;
    const short* vrow = vt + (((size_t)b * NH + h) * HD + i) * KPAD + kwb + g * 8;
    const float* cgb = ctr + (size_t)b * NQ * 2;
    short* plw = (short*)smem + w * (16 * 72);   // wave-private

    for (int kb = 0; kb < NQ; kb += 128) {
        // ---- QK^T (K frags from global) + distance mask ----
        float st[16];
#pragma unroll
        for (int kc = 0; kc < 4; ++kc) {
            int kr = min(kb + kwb + kc * 16 + i, NQ - 1);
            bf16x8 af = *(const bf16x8*)(kgb + (size_t)kr * E3);
            f32x4 zero = {};
            f32x4 s = __builtin_amdgcn_mfma_f32_16x16x32_bf16(af, qf, zero, 0, 0, 0);
            int kidx = kb + kwb + kc * 16 + 4 * g;
            float4 cA = *(const float4*)(cgb + kidx * 2);
            float4 cB = *(const float4*)(cgb + kidx * 2 + 4);
            float cxv[4] = {cA.x, cA.z, cB.x, cB.z};
            float cyv[4] = {cA.y, cA.w, cB.y, cB.w};
#pragma unroll
            for (int r = 0; r < 4; ++r) {
                float dx = cqx - cxv[r], dy = cqy - cyv[r];
                float dist = __builtin_amdgcn_sqrtf(dx * dx + dy * dy);
                float sc = s[r] * SL2E - dist * bql;
                st[kc * 4 + r] = (kidx + r < NQ) ? sc : -1e30f;
            }
        }

        // ---- online softmax (15 in-lane max + 2 shfl) ----
        float vm = st[0];
#pragma unroll
        for (int x = 1; x < 16; ++x) vm = fmaxf(vm, st[x]);
        vm = fmaxf(vm, __shfl_xor(vm, 16));
        vm = fmaxf(vm, __shfl_xor(vm, 32));
        float mnew = fmaxf(mcur, vm);
        float alpha = __builtin_amdgcn_exp2f(mcur - mnew);
        mcur = mnew;
        float rs = 0.f;
#pragma unroll
        for (int x = 0; x < 16; ++x) {
            st[x] = __builtin_amdgcn_exp2f(st[x] - mnew);
            rs += st[x];
        }
        rs += __shfl_xor(rs, 16);
        rs += __shfl_xor(rs, 32);
        lsum = lsum * alpha + rs;
#pragma unroll
        for (int r = 0; r < 4; ++r) { o0[r] *= alpha; o1[r] *= alpha; }

        // ---- P -> wave-private LDS (R2-proven layout), dword writes ----
#pragma unroll
        for (int kc = 0; kc < 4; ++kc) {
            *(unsigned*)&plw[i * 72 + kc * 16 + 4 * g]     = pack2bf(st[kc * 4 + 0], st[kc * 4 + 1]);
            *(unsigned*)&plw[i * 72 + kc * 16 + 4 * g + 2] = pack2bf(st[kc * 4 + 2], st[kc * 4 + 3]);
        }

        // ---- V^T fragments straight from global (L2-resident) + PV ----
        const short* vp = vrow + kb;
        bf16x8 vf00 = *(const bf16x8*)(vp);                   // d 0-15,  keys 0-31
        bf16x8 vf01 = *(const bf16x8*)(vp + 32);              // d 0-15,  keys 32-63
        bf16x8 vf10 = *(const bf16x8*)(vp + 16 * KPAD);       // d 16-31, keys 0-31
        bf16x8 vf11 = *(const bf16x8*)(vp + 16 * KPAD + 32);  // d 16-31, keys 32-63

        bf16x8 pbf0 = *(const bf16x8*)&plw[i * 72 + 0 * 32 + g * 8];
        bf16x8 pbf1 = *(const bf16x8*)&plw[i * 72 + 1 * 32 + g * 8];

        o0 = __builtin_amdgcn_mfma_f32_16x16x32_bf16(vf00, pbf0, o0, 0, 0, 0);
        o1 = __builtin_amdgcn_mfma_f32_16x16x32_bf16(vf10, pbf0, o1, 0, 0, 0);
        o0 = __builtin_amdgcn_mfma_f32_16x16x32_bf16(vf01, pbf1, o0, 0, 0, 0);
        o1 = __builtin_amdgcn_mfma_f32_16x16x32_bf16(vf11, pbf1, o1, 0, 0, 0);
    }

    // ---- merge the two key-splits per q-group (overlays plw -> barrier first) ----
    __syncthreads();
    float* mrg = (float*)smem;                 // [4][64][10]
    float* my = mrg + (w * 64 + lane) * 10;
    my[0] = mcur; my[1] = lsum;
#pragma unroll
    for (int r = 0; r < 4; ++r) { my[2 + r] = o0[r]; my[6 + r] = o1[r]; }
    __syncthreads();
    const float* pr = mrg + ((w ^ 1) * 64 + lane) * 10;
    float m2 = pr[0], l2 = pr[1];
    float mN = fmaxf(mcur, m2);
    float a1 = __builtin_amdgcn_exp2f(mcur - mN);
    float a2 = __builtin_amdgcn_exp2f(m2 - mN);
    float inv = 1.f / (lsum * a1 + l2 * a2);
    int hh = w & 1;                            // this wave writes d-half hh
    f32x4 mine = hh ? o1 : o0;
    if (q < NQ) {
        short4 outv;
        float vals[4];
#pragma unroll
        for (int r = 0; r < 4; ++r) vals[r] = (mine[r] * a1 + pr[2 + hh * 4 + r] * a2) * inv;
        outv.x = f2bf(vals[0]); outv.y = f2bf(vals[1]);
        outv.z = f2bf(vals[2]); outv.w = f2bf(vals[3]);
        *(short4*)&attnb[(size_t)(b * NQ + q) * DIM + h * HD + hh * 16 + 4 * g] = outv;
    }
}

extern "C" void kernel_launch(void* const* d_in, const int* in_sizes, int n_in,
                              void* d_out, int out_size, void* d_ws, size_t ws_size,
                              hipStream_t stream) {
    const float* bbox  = (const float*)d_in[0];
    const float* feat  = (const float*)d_in[1];
    const float* bw    = (const float*)d_in[2];
    const float* bb    = (const float*)d_in[3];
    const float* in_w  = (const float*)d_in[4];
    const float* in_b  = (const float*)d_in[5];
    const float* out_w = (const float*)d_in[6];
    const float* out_b = (const float*)d_in[7];
    float* out = (float*)d_out;

    char* ws = (char*)d_ws;
    size_t off = 0;
    auto alloc = [&](size_t bytes) { void* p = ws + off; off += (bytes + 255) & ~255ull; return p; };
    short* qkvb  = (short*)alloc((size_t)MROWS * E3 * 2);
    short* vtb   = (short*)alloc((size_t)BC * NH * HD * KPAD * 2);
    short* attnb = (short*)alloc((size_t)MROWS * DIM * 2);
    float* betab = (float*)alloc((size_t)BC * NH * NQ * 4);
    float* ctr   = (float*)alloc((size_t)BC * NQ * 2 * 4 + 1024);  // pad: masked tail reads
    (void)ws_size; (void)in_sizes; (void)n_in; (void)out_size;

    beta_ctr_kernel<<<MROWS / 4, 256, 0, stream>>>(feat, bw, bb, bbox, betab, ctr);
    gemm_k256<true, true, false, true><<<dim3(E3 / 64, MROWS / 64), 256, 0, stream>>>(feat, in_w, in_b, qkvb, E3, vtb);
    attn_kernel<<<dim3((NQ + 31) / 32, BC * NH), 256, 0, stream>>>(qkvb, vtb, betab, ctr, attnb);
    gemm_k256<false, true, true, false><<<dim3(DIM / 64, MROWS / 64), 256, 0, stream>>>(attnb, out_w, out_b, out, DIM, nullptr);
}

// Round 6
// 59.960 us; speedup vs baseline: 1.5236x; 1.5236x over previous
//
#include <hip/hip_runtime.h>
#include <hip/hip_bf16.h>

#define BC 4
#define NQ 1200
#define DIM 256
#define NH 8
#define HD 32
#define E3 768
#define MROWS (BC*NQ)
#define KPAD 1280
#define SCALE 0.17677669529663687f
#define L2E 1.4426950408889634f
#define SL2E (SCALE * L2E)

// VT2 global layout: [b][h][hh(2)][chunk(160)][d16(16)][8 keys]
#define VT2_PER_BH 40960
#define VT2_PER_HH 20480

typedef __attribute__((ext_vector_type(8))) short bf16x8;
typedef __attribute__((ext_vector_type(4))) float f32x4;

__device__ inline short f2bf(float f) {
    __hip_bfloat16 h = __float2bfloat16(f);
    return *reinterpret_cast<short*>(&h);
}
__device__ inline unsigned pack2bf(float a, float b) {
    unsigned ua = (unsigned short)f2bf(a);
    unsigned ub = (unsigned short)f2bf(b);
    return ua | (ub << 16);
}

// ---------------- beta (f32 exact) + center packing ----------------
__global__ void beta_ctr_kernel(const float* __restrict__ feat, const float* __restrict__ bw,
                                const float* __restrict__ bb, const float* __restrict__ bbox,
                                float* __restrict__ beta, float* __restrict__ ctr) {
    int gw = (blockIdx.x * 256 + threadIdx.x) >> 6;   // one wave per (b,n)
    int lane = threadIdx.x & 63;
    if (gw >= MROWS) return;
    const float* frow = feat + (size_t)gw * DIM;
    float acc[NH];
#pragma unroll
    for (int h = 0; h < NH; ++h) acc[h] = 0.f;
#pragma unroll
    for (int it = 0; it < DIM / 64; ++it) {
        int d = it * 64 + lane;
        float f = frow[d];
#pragma unroll
        for (int h = 0; h < NH; ++h) acc[h] += f * bw[h * DIM + d];
    }
#pragma unroll
    for (int h = 0; h < NH; ++h) {
#pragma unroll
        for (int off = 32; off; off >>= 1) acc[h] += __shfl_xor(acc[h], off);
    }
    int b = gw / NQ, n = gw % NQ;
#pragma unroll
    for (int h = 0; h < NH; ++h) {
        float v = acc[h] + bb[h];
        if (lane == h) beta[(b * NH + h) * NQ + n] = v;
    }
    if (lane == 0) {
        ctr[gw * 2]     = bbox[(size_t)gw * 10];
        ctr[gw * 2 + 1] = bbox[(size_t)gw * 10 + 1];
    }
}

// ---------------- GEMM: C[M,E] = A[M,256] * W[E,256]^T + bias ----------------
// QSCALE: scale W rows e<256 (the Q projection) by SCALE*log2e in f32 before bf16.
// VTOUT: rows e in [512,768) (V projection) go to VT2 chunked-transposed layout.
template<bool AF32, bool BF32, bool OUTF32, bool VTOUT, bool QSCALE>
__global__ __launch_bounds__(256) void gemm_k256(const void* __restrict__ Av,
                                                 const void* __restrict__ Bv,
                                                 const float* __restrict__ bias,
                                                 void* __restrict__ Cout, int Edim,
                                                 short* __restrict__ vtout) {
    __shared__ short as[64][40];
    __shared__ short bs[64][40];
    int m0 = blockIdx.y * 64, e0 = blockIdx.x * 64;
    int t = threadIdx.x, lane = t & 63, wid = t >> 6;
    int wr = (wid >> 1) * 32, wc = (wid & 1) * 32;
    f32x4 acc[2][2] = {};
    int lrow = t >> 2, lch = t & 3;
    const float qs = (QSCALE && e0 < DIM) ? SL2E : 1.f;

    for (int ks = 0; ks < DIM / 32; ++ks) {
        bf16x8 av, wv;
        if (AF32) {
            const float* A = (const float*)Av;
            float4 f0 = *(const float4*)(A + (size_t)(m0 + lrow) * DIM + ks * 32 + lch * 8);
            float4 f1 = *(const float4*)(A + (size_t)(m0 + lrow) * DIM + ks * 32 + lch * 8 + 4);
            av[0]=f2bf(f0.x); av[1]=f2bf(f0.y); av[2]=f2bf(f0.z); av[3]=f2bf(f0.w);
            av[4]=f2bf(f1.x); av[5]=f2bf(f1.y); av[6]=f2bf(f1.z); av[7]=f2bf(f1.w);
        } else {
            av = *(const bf16x8*)((const short*)Av + (size_t)(m0 + lrow) * DIM + ks * 32 + lch * 8);
        }
        if (BF32) {
            const float* B = (const float*)Bv;
            float4 f0 = *(const float4*)(B + (size_t)(e0 + lrow) * DIM + ks * 32 + lch * 8);
            float4 f1 = *(const float4*)(B + (size_t)(e0 + lrow) * DIM + ks * 32 + lch * 8 + 4);
            wv[0]=f2bf(f0.x*qs); wv[1]=f2bf(f0.y*qs); wv[2]=f2bf(f0.z*qs); wv[3]=f2bf(f0.w*qs);
            wv[4]=f2bf(f1.x*qs); wv[5]=f2bf(f1.y*qs); wv[6]=f2bf(f1.z*qs); wv[7]=f2bf(f1.w*qs);
        } else {
            wv = *(const bf16x8*)((const short*)Bv + (size_t)(e0 + lrow) * DIM + ks * 32 + lch * 8);
        }
        __syncthreads();
        *(bf16x8*)&as[lrow][lch * 8] = av;
        *(bf16x8*)&bs[lrow][lch * 8] = wv;
        __syncthreads();
#pragma unroll
        for (int sm = 0; sm < 2; ++sm) {
            bf16x8 af = *(const bf16x8*)&as[wr + sm * 16 + (lane & 15)][(lane >> 4) * 8];
#pragma unroll
            for (int sn = 0; sn < 2; ++sn) {
                bf16x8 bfv = *(const bf16x8*)&bs[wc + sn * 16 + (lane & 15)][(lane >> 4) * 8];
                acc[sm][sn] = __builtin_amdgcn_mfma_f32_16x16x32_bf16(af, bfv, acc[sm][sn], 0, 0, 0);
            }
        }
    }
#pragma unroll
    for (int sm = 0; sm < 2; ++sm)
#pragma unroll
        for (int sn = 0; sn < 2; ++sn) {
            int e = e0 + wc + sn * 16 + (lane & 15);
            float bv = bias[e];
            if (QSCALE && e < DIM) bv *= SL2E;
            float vals[4];
            int mbase = m0 + wr + sm * 16 + (lane >> 4) * 4;
#pragma unroll
            for (int r = 0; r < 4; ++r) vals[r] = acc[sm][sn][r] + bv;
            if (VTOUT && e >= 2 * DIM) {
                int dv = e - 2 * DIM;
                int hv = dv >> 5, dd = dv & 31;
                int hh = dd >> 4, di = dd & 15;
                int bb = mbase / NQ, nn = mbase - bb * NQ;   // 4-key group never crosses b
                short4 o;
                o.x = f2bf(vals[0]); o.y = f2bf(vals[1]);
                o.z = f2bf(vals[2]); o.w = f2bf(vals[3]);
                size_t off = (size_t)(bb * NH + hv) * VT2_PER_BH + hh * VT2_PER_HH
                           + (nn >> 3) * 128 + di * 8 + (nn & 7);
                *(short4*)&vtout[off] = o;
            } else {
#pragma unroll
                for (int r = 0; r < 4; ++r) {
                    int m = mbase + r;
                    if (OUTF32) ((float*)Cout)[(size_t)m * Edim + e] = vals[r];
                    else        ((short*)Cout)[(size_t)m * Edim + e] = f2bf(vals[r]);
                }
            }
        }
}

// ---------------- fused flash attention ----------------
// grid: (38, B*H); block 256 = 4 waves: wave = (qgroup<<1)|ksplit.
// Cooperative LDS staging (conflict-free 16B-block layouts), T14 reg-staged
// prefetch, T13 defer-max, Q pre-scaled in GEMM. Two barriers per tile.
#define KT_OFF 0
#define VT_OFF 8192
#define CK_OFF 16384
#define PL_OFF 17408
__global__ __launch_bounds__(256, 4) void attn_kernel(const short* __restrict__ qkv,
                                                      const short* __restrict__ vt2,
                                                      const float* __restrict__ beta,
                                                      const float* __restrict__ ctr,
                                                      short* __restrict__ attnb) {
    __shared__ __align__(16) char smem[25600];

    const int t = threadIdx.x, lane = t & 63, w = t >> 6;
    const int g = lane >> 4, i = lane & 15;
    const int qg = w >> 1, ksp = w & 1;
    const int bh = blockIdx.y, b = bh >> 3, h = bh & 7;
    const int q0 = blockIdx.x * 32 + qg * 16;
    const int q = q0 + i, qc = min(q, NQ - 1);
    const int kwb = ksp * 64;
    const int bq = b * NQ;

    bf16x8 qf = *(const bf16x8*)(qkv + (size_t)(bq + qc) * E3 + h * HD + g * 8);  // pre-scaled
    const float cqx = ctr[(bq + qc) * 2];
    const float cqy = ctr[(bq + qc) * 2 + 1];
    const float nbql = -beta[(b * NH + h) * NQ + qc] * L2E;

    float mcur = -1e30f, lsum = 0.f;
    f32x4 o0 = {}, o1 = {};

    const short* kgb = qkv + (size_t)bq * E3 + DIM + h * HD;
    const short* vgb = vt2 + (size_t)bh * VT2_PER_BH;
    const float* cgb = ctr + (size_t)bq * 2;

    bf16x8 sk0, sk1, sv0, sv1;
    float2 sc2;

    auto stage_load = [&](int kb) {
        int i0 = t, i1 = t + 256;
        int r0 = min(kb + ((i0 >> 6) << 4) + (i0 & 15), NQ - 1);
        int r1 = min(kb + ((i1 >> 6) << 4) + (i1 & 15), NQ - 1);
        sk0 = *(const bf16x8*)(kgb + (size_t)r0 * E3 + ((i0 >> 4) & 3) * 8);
        sk1 = *(const bf16x8*)(kgb + (size_t)r1 * E3 + ((i1 >> 4) & 3) * 8);
        sv0 = *(const bf16x8*)(vgb + (i0 >> 8) * VT2_PER_HH + ((kb >> 3) + ((i0 >> 4) & 15)) * 128 + (i0 & 15) * 8);
        sv1 = *(const bf16x8*)(vgb + (i1 >> 8) * VT2_PER_HH + ((kb >> 3) + ((i1 >> 4) & 15)) * 128 + (i1 & 15) * 8);
        if (t < 128) {
            int ky = min(kb + t, NQ - 1);
            sc2 = *(const float2*)(cgb + ky * 2);
        }
    };
    auto stage_write = [&]() {
        *(bf16x8*)&smem[KT_OFF + t * 16]         = sk0;
        *(bf16x8*)&smem[KT_OFF + (t + 256) * 16] = sk1;
        *(bf16x8*)&smem[VT_OFF + t * 16]         = sv0;
        *(bf16x8*)&smem[VT_OFF + (t + 256) * 16] = sv1;
        if (t < 128) *(float2*)&smem[CK_OFF + t * 8] = sc2;
    };

    stage_load(0);
    stage_write();
    __syncthreads();

    for (int kb = 0; kb < NQ; kb += 128) {
        const bool haveNext = (kb + 128 < NQ);
        const bool tail = (kb + 128 > NQ);
        if (haveNext) stage_load(kb + 128);   // issue early; latency hides under compute

        // ---- QK^T + distance mask (conflict-free K frags) ----
        float st[16];
#pragma unroll
        for (int kcl = 0; kcl < 4; ++kcl) {
            bf16x8 af = *(const bf16x8*)&smem[KT_OFF + ((((ksp * 4 + kcl) << 6) + lane) << 4)];
            f32x4 zero = {};
            f32x4 s = __builtin_amdgcn_mfma_f32_16x16x32_bf16(af, qf, zero, 0, 0, 0);
            int lk = kwb + kcl * 16 + 4 * g;
            float4 cA = *(const float4*)&smem[CK_OFF + lk * 8];
            float4 cB = *(const float4*)&smem[CK_OFF + lk * 8 + 16];
            float cxv[4] = {cA.x, cA.z, cB.x, cB.z};
            float cyv[4] = {cA.y, cA.w, cB.y, cB.w};
#pragma unroll
            for (int r = 0; r < 4; ++r) {
                float dx = cqx - cxv[r], dy = cqy - cyv[r];
                float d2 = __builtin_fmaf(dx, dx, dy * dy);
                float dist = __builtin_amdgcn_sqrtf(d2);
                st[kcl * 4 + r] = __builtin_fmaf(dist, nbql, s[r]);
            }
            if (tail) {
#pragma unroll
                for (int r = 0; r < 4; ++r)
                    if (kb + lk + r >= NQ) st[kcl * 4 + r] = -1e30f;
            }
        }

        // ---- online softmax: 15 in-lane max + 2 shfl, T13 defer-max ----
        float vm = st[0];
#pragma unroll
        for (int x = 1; x < 16; ++x) vm = fmaxf(vm, st[x]);
        vm = fmaxf(vm, __shfl_xor(vm, 16));
        vm = fmaxf(vm, __shfl_xor(vm, 32));
        if (!__all(vm <= mcur + 8.0f)) {
            float mnew = fmaxf(mcur, vm);
            float al = __builtin_amdgcn_exp2f(mcur - mnew);
            mcur = mnew;
            lsum *= al;
#pragma unroll
            for (int r = 0; r < 4; ++r) { o0[r] *= al; o1[r] *= al; }
        }
        float rs = 0.f;
#pragma unroll
        for (int x = 0; x < 16; ++x) {
            st[x] = __builtin_amdgcn_exp2f(st[x] - mcur);
            rs += st[x];
        }
        rs += __shfl_xor(rs, 16);
        rs += __shfl_xor(rs, 32);
        lsum += rs;

        // ---- P -> wave-private LDS, chunked layout [c][q][8] ----
#pragma unroll
        for (int kcl = 0; kcl < 4; ++kcl) {
            int offb = PL_OFF + (((w << 10) + ((2 * kcl + (g >> 1)) << 7) + (i << 3) + ((g & 1) << 2)) << 1);
            *(unsigned*)&smem[offb]     = pack2bf(st[kcl * 4 + 0], st[kcl * 4 + 1]);
            *(unsigned*)&smem[offb + 4] = pack2bf(st[kcl * 4 + 2], st[kcl * 4 + 3]);
        }

        // ---- PV (conflict-free V^T + P frags) ----
#pragma unroll
        for (int kc2 = 0; kc2 < 2; ++kc2) {
            bf16x8 pbf = *(const bf16x8*)&smem[PL_OFF + (((w << 10) + ((kc2 * 4 + g) << 7) + (i << 3)) << 1)];
            int vidx = ((8 * ksp + 4 * kc2 + g) << 4) + i;
            bf16x8 vf0 = *(const bf16x8*)&smem[VT_OFF + (vidx << 4)];
            bf16x8 vf1 = *(const bf16x8*)&smem[VT_OFF + ((256 + vidx) << 4)];
            o0 = __builtin_amdgcn_mfma_f32_16x16x32_bf16(vf0, pbf, o0, 0, 0, 0);
            o1 = __builtin_amdgcn_mfma_f32_16x16x32_bf16(vf1, pbf, o1, 0, 0, 0);
        }

        if (haveNext) {
            __syncthreads();     // all waves done reading current tile
            stage_write();
            __syncthreads();     // next tile visible
        }
    }

    // ---- merge the two key-splits per q-group (overlays smem -> barrier) ----
    __syncthreads();
    float* mrg = (float*)smem;                 // [4][64][10]
    float* my = mrg + (w * 64 + lane) * 10;
    my[0] = mcur; my[1] = lsum;
#pragma unroll
    for (int r = 0; r < 4; ++r) { my[2 + r] = o0[r]; my[6 + r] = o1[r]; }
    __syncthreads();
    const float* pr = mrg + ((w ^ 1) * 64 + lane) * 10;
    float m2 = pr[0], l2 = pr[1];
    float mN = fmaxf(mcur, m2);
    float a1 = __builtin_amdgcn_exp2f(mcur - mN);
    float a2 = __builtin_amdgcn_exp2f(m2 - mN);
    float inv = 1.f / (lsum * a1 + l2 * a2);
    int hh = w & 1;                            // this wave writes d-half hh
    f32x4 mine = hh ? o1 : o0;
    if (q < NQ) {
        short4 outv;
        float vals[4];
#pragma unroll
        for (int r = 0; r < 4; ++r) vals[r] = (mine[r] * a1 + pr[2 + hh * 4 + r] * a2) * inv;
        outv.x = f2bf(vals[0]); outv.y = f2bf(vals[1]);
        outv.z = f2bf(vals[2]); outv.w = f2bf(vals[3]);
        *(short4*)&attnb[(size_t)(bq + q) * DIM + h * HD + hh * 16 + 4 * g] = outv;
    }
}

extern "C" void kernel_launch(void* const* d_in, const int* in_sizes, int n_in,
                              void* d_out, int out_size, void* d_ws, size_t ws_size,
                              hipStream_t stream) {
    const float* bbox  = (const float*)d_in[0];
    const float* feat  = (const float*)d_in[1];
    const float* bw    = (const float*)d_in[2];
    const float* bb    = (const float*)d_in[3];
    const float* in_w  = (const float*)d_in[4];
    const float* in_b  = (const float*)d_in[5];
    const float* out_w = (const float*)d_in[6];
    const float* out_b = (const float*)d_in[7];
    float* out = (float*)d_out;

    char* ws = (char*)d_ws;
    size_t off = 0;
    auto alloc = [&](size_t bytes) { void* p = ws + off; off += (bytes + 255) & ~255ull; return p; };
    short* qkvb  = (short*)alloc((size_t)MROWS * E3 * 2);
    short* vtb   = (short*)alloc((size_t)BC * NH * VT2_PER_BH * 2);
    short* attnb = (short*)alloc((size_t)MROWS * DIM * 2);
    float* betab = (float*)alloc((size_t)BC * NH * NQ * 4);
    float* ctr   = (float*)alloc((size_t)BC * NQ * 2 * 4 + 1024);
    (void)ws_size; (void)in_sizes; (void)n_in; (void)out_size;

    beta_ctr_kernel<<<MROWS / 4, 256, 0, stream>>>(feat, bw, bb, bbox, betab, ctr);
    gemm_k256<true, true, false, true, true><<<dim3(E3 / 64, MROWS / 64), 256, 0, stream>>>(feat, in_w, in_b, qkvb, E3, vtb);
    attn_kernel<<<dim3((NQ + 31) / 32, BC * NH), 256, 0, stream>>>(qkvb, vtb, betab, ctr, attnb);
    gemm_k256<false, true, true, false, false><<<dim3(DIM / 64, MROWS / 64), 256, 0, stream>>>(attnb, out_w, out_b, out, DIM, nullptr);
}